// Round 11
// baseline (157.243 us; speedup 1.0000x reference)
//
#include <hip/hip_runtime.h>

constexpr int HD = 128;       // hidden size
constexpr int BROWS = 64;     // rows per bucket == rows per mega-block
constexpr int CAP = 2048;     // entries per bucket slot (= LDS sort capacity)
constexpr int NBMAX = 2048;   // max buckets (N <= 131072)
constexpr int EPB = 16384;    // edges per scatter block
constexpr int SLOT_STRIDE = 4096;   // int2 entries per bucket window in d_out
constexpr int SLOT_BYTES = 32768;   // 64 rows * 128 * 4 B

typedef __attribute__((ext_vector_type(8))) short short8v;  // 8 bf16 (4 VGPR)
typedef __attribute__((ext_vector_type(4))) float f32x4;
typedef __attribute__((ext_vector_type(2))) float f32x2;

__device__ __forceinline__ int rl(int v, int j) {
    return __builtin_amdgcn_readlane(v, j);
}
__device__ __forceinline__ float rlf(int v, int j) {
    return __uint_as_float((unsigned)__builtin_amdgcn_readlane(v, j));
}
__device__ __forceinline__ unsigned f2bf(float f) {  // f32 -> bf16 bits, RNE
    unsigned u = __float_as_uint(f);
    return (u + 0x7fffu + ((u >> 16) & 1u)) >> 16;
}
__device__ __forceinline__ f32x2 bf2f(unsigned u) {
    f32x2 r = {__uint_as_float(u << 16), __uint_as_float(u & 0xffff0000u)};
    return r;
}

// meta.x layout: bits[31:26] = local row (0..63), bits[25:8] = col*256 (byte
// offset of the xb row), bits[7:0] = 0.
#define META_OFF_MASK 0x03FFFF00

// ---------------------------------------------------------------------------
// init: zero the NB relative bucket cursors.
// ---------------------------------------------------------------------------
__global__ void init_kernel(int* __restrict__ cursor, int NB) {
    int i = blockIdx.x * 1024 + threadIdx.x;
    if (i < NB) cursor[i] = 0;
}

// ---------------------------------------------------------------------------
// build: three independent block-ranges in one launch (co-scheduled).
//  [0, PB)        : per-row L1 norm of x; pack xb = bf16x2(x*rnorm); xnorm
//  [PB, PB+16)    : Wb bf16 pack, B-fragment layout, XOR-swizzled
//  [PB+16, +SB)   : two-pass ranked scatter of edges into per-bucket slots
//                   (slots live in d_out; last bucket's slot in ws)
// ---------------------------------------------------------------------------
__global__ void __launch_bounds__(512) build_kernel(
    const float* __restrict__ x, unsigned* __restrict__ xb,
    float* __restrict__ xnorm, const float* __restrict__ W,
    unsigned* __restrict__ Wb, const int* __restrict__ rows,
    const int* __restrict__ cols, const float* __restrict__ vals,
    int* __restrict__ cursor, int2* __restrict__ outslots,
    int2* __restrict__ lastslot, int N, int E, int PB, int NB) {
    int bid = blockIdx.x;
    int tid = threadIdx.x;
    if (bid < PB) {
        int row = bid * 8 + (tid >> 6);
        int lane = tid & 63;
        if (row >= N) return;
        float2 v = *((const float2*)(x + (size_t)row * HD) + lane);
        float s = fabsf(v.x) + fabsf(v.y);
#pragma unroll
        for (int m = 1; m < 64; m <<= 1) s += __shfl_xor(s, m, 64);
        float nm = fmaxf(s, 1e-12f);
        float rn = 1.0f / nm;
        if (lane == 0) xnorm[row] = nm;
        unsigned lo = f2bf(v.x * rn), hi = f2bf(v.y * rn);
        xb[(size_t)row * 64 + lane] = lo | (hi << 16);
    } else if (bid < PB + 16) {
        int t = (bid - PB) * 512 + tid;  // 0..8191 => (col, k2)
        int col = t >> 6, k2 = t & 63;
        float w0 = W[col * HD + 2 * k2];
        float w1 = W[col * HD + 2 * k2 + 1];
        unsigned pk = f2bf(w0) | (f2bf(w1) << 16);
        int byte = (col * 256 + k2 * 4) ^ ((col & 7) << 4);
        *(unsigned*)((char*)Wb + byte) = pk;
    } else {
        int sb = bid - PB - 16;
        if (NB <= NBMAX) {
            __shared__ int lbin[NBMAX];
            __shared__ int lbase[NBMAX];
            __shared__ unsigned short rk16[EPB];
            for (int i = tid; i < NBMAX; i += 512) lbin[i] = 0;
            __syncthreads();
            const int4* rows4 = (const int4*)rows;
            int E4 = E >> 2;
            int base4 = sb * (EPB / 4);
            // pass A: local ranks
#pragma unroll
            for (int i = 0; i < 8; ++i) {
                int e4 = base4 + i * 512 + tid;
                if (e4 < E4) {
                    int4 r = rows4[e4];
                    int li = (i * 512 + tid) * 4;
                    rk16[li + 0] = (unsigned short)atomicAdd(&lbin[r.x >> 6], 1);
                    rk16[li + 1] = (unsigned short)atomicAdd(&lbin[r.y >> 6], 1);
                    rk16[li + 2] = (unsigned short)atomicAdd(&lbin[r.z >> 6], 1);
                    rk16[li + 3] = (unsigned short)atomicAdd(&lbin[r.w >> 6], 1);
                }
            }
            __syncthreads();
            // reserve contiguous ranges (relative cursors)
            for (int i = tid; i < NB; i += 512) {
                int c = lbin[i];
                if (c) lbase[i] = atomicAdd(&cursor[i], c);
            }
            __syncthreads();
            // pass B: write edges to reserved slots
            const int4* cols4 = (const int4*)cols;
            const float4* vals4 = (const float4*)vals;
#pragma unroll
            for (int i = 0; i < 8; ++i) {
                int e4 = base4 + i * 512 + tid;
                if (e4 < E4) {
                    int4 r4 = rows4[e4];
                    int4 c4 = cols4[e4];
                    float4 v4 = vals4[e4];
                    int li = (i * 512 + tid) * 4;
                    int ra[4] = {r4.x, r4.y, r4.z, r4.w};
                    int ca[4] = {c4.x, c4.y, c4.z, c4.w};
                    float va[4] = {v4.x, v4.y, v4.z, v4.w};
#pragma unroll
                    for (int k = 0; k < 4; ++k) {
                        int r = ra[k];
                        int bkt = r >> 6;
                        int idx = lbase[bkt] + rk16[li + k];
                        if (idx < CAP) {
                            int2* sp = (bkt == NB - 1)
                                           ? lastslot
                                           : outslots + (size_t)bkt * SLOT_STRIDE;
                            sp[idx] = make_int2((ca[k] << 8) | ((r & 63) << 26),
                                                __float_as_int(va[k]));
                        }
                    }
                }
            }
            if (sb == 0) {  // scalar tail (E % 4): direct cursor append
                for (int e = (E & ~3) + tid; e < E; e += 512) {
                    int r = rows[e];
                    int bkt = r >> 6;
                    int rel = atomicAdd(&cursor[bkt], 1);
                    if (rel < CAP) {
                        int2* sp = (bkt == NB - 1)
                                       ? lastslot
                                       : outslots + (size_t)bkt * SLOT_STRIDE;
                        sp[rel] = make_int2((cols[e] << 8) | ((r & 63) << 26),
                                            __float_as_int(vals[e]));
                    }
                }
            }
        } else {  // fallback: per-edge cursor atomics
            int base = sb * EPB;
            for (int i = 0; i < 32; ++i) {
                int e = base + i * 512 + tid;
                if (e >= E) break;
                int r = rows[e];
                int bkt = r >> 6;
                int rel = atomicAdd(&cursor[bkt], 1);
                if (rel < CAP) {
                    int2* sp = (bkt == NB - 1)
                                   ? lastslot
                                   : outslots + (size_t)bkt * SLOT_STRIDE;
                    sp[rel] = make_int2((cols[e] << 8) | ((r & 63) << 26),
                                        __float_as_int(vals[e]));
                }
            }
        }
    }
}

// ---------------------------------------------------------------------------
// mega: per 64-row bucket (1024 threads = 16 waves):
//  1. slot edges (in d_out window) -> regs; in-LDS 64-bin counting sort
//  2. gather: each wave accumulates 4 f-rows (f32x2 FMA, 4-wide unroll)
//  3. f -> bf16 -> swizzled LDS A-tile
//  4. GEMM via mfma_f32_16x16x32_bf16 (wave = 16x32 output tile)
//  5. bias, row-L1 reduce, relu, residual (reconstructed from xb*xnorm), store
// Safe d_out reuse: the block fully consumes its slot (phase 1) before any
// out-write, and only ever writes its own 32KB window.
// ---------------------------------------------------------------------------
__global__ void __launch_bounds__(1024) mega_kernel(
    const unsigned* __restrict__ xb, const float* __restrict__ xnorm,
    const int* __restrict__ cursor, const int2* __restrict__ lastslot,
    const unsigned* __restrict__ Wb, const float* __restrict__ bias,
    const float* __restrict__ tsp, float* out, int N, int NB) {
    __shared__ char wb_raw[HD * HD * 2];     // 32 KiB bf16 W, B-layout, swz
    __shared__ char fb_raw[BROWS * HD * 2];  // 16 KiB bf16 F, A-layout, swz
    __shared__ int2 sorted[CAP];             // 16 KiB
    __shared__ int lcnt[BROWS], lbeg[BROWS], lcur[BROWS];
    __shared__ float rowsum[BROWS];

    int tid = threadIdx.x;
    int bid = blockIdx.x;
    const int2* slot = (bid == NB - 1)
                           ? lastslot
                           : (const int2*)((const char*)out +
                                           (size_t)bid * SLOT_BYTES);
    int ct = cursor[bid];
    if (ct > CAP) ct = CAP;

    if (tid < BROWS) lcnt[tid] = 0;

    // phase 1: slot edges -> registers (slot fully consumed here)
    int2 m0 = make_int2(0, 0), m1 = make_int2(0, 0);
    bool e0 = tid < ct, e1 = tid + 1024 < ct;
    if (e0) m0 = slot[tid];
    if (e1) m1 = slot[tid + 1024];
    __syncthreads();

    // phase 2: LDS histogram of local rows
    if (e0) atomicAdd(&lcnt[(unsigned)m0.x >> 26], 1);
    if (e1) atomicAdd(&lcnt[(unsigned)m1.x >> 26], 1);
    __syncthreads();

    // phase 3: wave 0 exclusive-scans the 64 counts
    if (tid < 64) {
        int c = lcnt[tid];
        int s = c;
#pragma unroll
        for (int m = 1; m < 64; m <<= 1) {
            int t2 = __shfl_up(s, m, 64);
            if (tid >= m) s += t2;
        }
        lbeg[tid] = s - c;
        lcur[tid] = s - c;
    }
    __syncthreads();

    // phase 4: scatter edges into LDS-sorted local CSR (+ stage Wb)
    if (e0) {
        int p = atomicAdd(&lcur[(unsigned)m0.x >> 26], 1);
        if (p < CAP) sorted[p] = m0;
    }
    if (e1) {
        int p = atomicAdd(&lcur[(unsigned)m1.x >> 26], 1);
        if (p < CAP) sorted[p] = m1;
    }
    {
        const float4* s4 = (const float4*)Wb;
        float4* d4 = (float4*)wb_raw;
        for (int i = tid; i < HD * HD * 2 / 16; i += 1024) d4[i] = s4[i];
    }
    __syncthreads();

    int lane = tid & 63;
    int wid = tid >> 6;
    float ts = tsp[0];
    const char* xbl = (const char*)xb + (lane << 2);

    // ---- gather: accumulate 4 f-rows (f32x2) per wave ----
    float a0[4], a1[4];
#pragma unroll
    for (int rr = 0; rr < 4; ++rr) {
        int lr = wid * 4 + rr;
        int beg = lbeg[lr], cnt = lcnt[lr];
        f32x2 pq0 = {0.f, 0.f}, pq1 = {0.f, 0.f};
        for (int jb = 0; jb < cnt; jb += 64) {
            int rem = cnt - jb;
            if (rem > 64) rem = 64;
            int2 meta = make_int2(0, 0);
            if (lane < rem) meta = sorted[beg + jb + lane];
            int j = 0;
            for (; j + 4 <= rem; j += 4) {
                int o0 = rl(meta.x, j) & META_OFF_MASK;
                int o1 = rl(meta.x, j + 1) & META_OFF_MASK;
                int o2 = rl(meta.x, j + 2) & META_OFF_MASK;
                int o3 = rl(meta.x, j + 3) & META_OFF_MASK;
                float s0 = rlf(meta.y, j), s1 = rlf(meta.y, j + 1);
                float s2 = rlf(meta.y, j + 2), s3 = rlf(meta.y, j + 3);
                unsigned u0 = *(const unsigned*)(xbl + o0);
                unsigned u1 = *(const unsigned*)(xbl + o1);
                unsigned u2 = *(const unsigned*)(xbl + o2);
                unsigned u3 = *(const unsigned*)(xbl + o3);
                pq0 += bf2f(u0) * s0;
                pq1 += bf2f(u1) * s1;
                pq0 += bf2f(u2) * s2;
                pq1 += bf2f(u3) * s3;
            }
            for (; j < rem; ++j) {
                int o0 = rl(meta.x, j) & META_OFF_MASK;
                float s0 = rlf(meta.y, j);
                unsigned u0 = *(const unsigned*)(xbl + o0);
                pq0 += bf2f(u0) * s0;
            }
        }
        a0[rr] = pq0.x + pq1.x;
        a1[rr] = pq0.y + pq1.y;
    }

    // ---- phase C: f -> bf16 swizzled LDS A-tile; init rowsum ----
#pragma unroll
    for (int rr = 0; rr < 4; ++rr) {
        int row = wid * 4 + rr;  // local row
        unsigned pk = f2bf(a0[rr]) | (f2bf(a1[rr]) << 16);
        int byte = (row * 256 + lane * 4) ^ ((row & 7) << 4);
        *(unsigned*)(fb_raw + byte) = pk;
    }
    if (tid < BROWS) rowsum[tid] = 0.f;
    __syncthreads();

    // ---- MFMA GEMM: wave -> 16-row x 32-col output tile ----
    int rt = wid >> 2;        // row-tile 0..3
    int ct0 = (wid & 3) * 2;  // first col-tile (of 8)
    int c = lane & 15;
    int kg = lane >> 4;
    int arow = rt * 16 + c;
    int bcol0 = ct0 * 16 + c;
    int bcol1 = bcol0 + 16;
    f32x4 acc0 = {0.f, 0.f, 0.f, 0.f}, acc1 = {0.f, 0.f, 0.f, 0.f};
#pragma unroll
    for (int kk = 0; kk < 4; ++kk) {
        int ka = kg * 16 + kk * 64;  // byte offset of this lane's k-chunk
        short8v af = *(const short8v*)(fb_raw +
                                       ((arow * 256 + ka) ^ ((arow & 7) << 4)));
        short8v bf0 = *(const short8v*)(wb_raw +
                                        ((bcol0 * 256 + ka) ^ ((bcol0 & 7) << 4)));
        short8v bf1 = *(const short8v*)(wb_raw +
                                        ((bcol1 * 256 + ka) ^ ((bcol1 & 7) << 4)));
        acc0 = __builtin_amdgcn_mfma_f32_16x16x32_bf16(af, bf0, acc0, 0, 0, 0);
        acc1 = __builtin_amdgcn_mfma_f32_16x16x32_bf16(af, bf1, acc1, 0, 0, 0);
    }

    // ---- epilogue: bias, row-L1 reduce, normalize, relu, residual ----
    float bias0 = bias[bcol0];
    float bias1 = bias[bcol1];
    float g0r[4], g1r[4];
#pragma unroll
    for (int r = 0; r < 4; ++r) {
        float v0 = acc0[r] + bias0;
        float v1 = acc1[r] + bias1;
        g0r[r] = v0;
        g1r[r] = v1;
        float s = fabsf(v0) + fabsf(v1);
        s += __shfl_xor(s, 1, 64);
        s += __shfl_xor(s, 2, 64);
        s += __shfl_xor(s, 4, 64);
        s += __shfl_xor(s, 8, 64);
        if (c == 0) atomicAdd(&rowsum[rt * 16 + kg * 4 + r], s);
    }
    __syncthreads();
#pragma unroll
    for (int r = 0; r < 4; ++r) {
        int lrow = rt * 16 + kg * 4 + r;
        int row = bid * BROWS + lrow;
        if (row < N) {
            float rn = 1.0f / fmaxf(rowsum[lrow], 1e-12f);
            float G0 = fmaxf(g0r[r] * rn, 0.f);
            float G1 = fmaxf(g1r[r] * rn, 0.f);
            // residual reconstruction: x = bf16(x * (1/norm)) * norm
            float nm = xnorm[row];
            unsigned u0 = xb[(size_t)row * 64 + ct0 * 8 + (c >> 1)];
            unsigned u1 = xb[(size_t)row * 64 + ct0 * 8 + 8 + (c >> 1)];
            unsigned h0 = (c & 1) ? (u0 & 0xffff0000u) : (u0 << 16);
            unsigned h1 = (c & 1) ? (u1 & 0xffff0000u) : (u1 << 16);
            float x0 = __uint_as_float(h0) * nm;
            float x1 = __uint_as_float(h1) * nm;
            out[(size_t)row * HD + bcol0] = fmaf(ts, G0, x0);
            out[(size_t)row * HD + bcol1] = fmaf(ts, G1, x1);
        }
    }
}

extern "C" void kernel_launch(void* const* d_in, const int* in_sizes, int n_in,
                              void* d_out, int out_size, void* d_ws,
                              size_t ws_size, hipStream_t stream) {
    const float* x = (const float*)d_in[0];
    const int* Ar = (const int*)d_in[1];
    const int* Ac = (const int*)d_in[2];
    const float* Av = (const float*)d_in[3];
    const float* W = (const float*)d_in[4];
    const float* b = (const float*)d_in[5];
    const float* ts = (const float*)d_in[6];

    int N = in_sizes[0] / HD;
    int E = in_sizes[1];
    float* out = (float*)d_out;

    int NB = (N + BROWS - 1) / BROWS;

    char* ws = (char*)d_ws;
    size_t o = 0;
    auto take = [&](size_t bytes) {
        void* p = ws + o;
        o += (bytes + 511) & ~(size_t)511;
        return p;
    };
    int* cursor = (int*)take((size_t)NB * 4);
    float* xnorm = (float*)take((size_t)N * 4);
    unsigned* Wb = (unsigned*)take((size_t)HD * HD * 2);
    int2* lastslot = (int2*)take((size_t)CAP * 8);
    unsigned* xb = (unsigned*)take((size_t)N * 64 * 4);
    // total ws use ~26.3 MB (well under proven >=40 MB)

    int PB = (N + 7) / 8;
    int SB = (E + EPB - 1) / EPB;

    init_kernel<<<(NB + 1023) / 1024, 1024, 0, stream>>>(cursor, NB);
    build_kernel<<<PB + 16 + SB, 512, 0, stream>>>(
        x, xb, xnorm, W, Wb, Ar, Ac, Av, cursor, (int2*)d_out, lastslot, N, E,
        PB, NB);
    mega_kernel<<<NB, 1024, 0, stream>>>(xb, xnorm, cursor, lastslot, Wb, b, ts,
                                         out, N, NB);
}

// Round 12
// 132.996 us; speedup vs baseline: 1.1823x; 1.1823x over previous
//
#include <hip/hip_runtime.h>

constexpr int HD = 128;       // hidden size
constexpr int BROWS = 64;     // rows per bucket == rows per mega-block
constexpr int CAP = 2048;     // entries per bucket slot (= LDS sort capacity)
constexpr int NBMAX = 2048;   // max buckets (N <= 131072)
constexpr int EPB = 16384;    // edges per scatter block
constexpr int SLOT_STRIDE = 4096;   // int2 entries per bucket window in d_out
constexpr int SLOT_BYTES = 32768;   // 64 rows * 128 * 4 B

typedef __attribute__((ext_vector_type(8))) short short8v;  // 8 bf16 (4 VGPR)
typedef __attribute__((ext_vector_type(4))) float f32x4;
typedef __attribute__((ext_vector_type(2))) float f32x2;

__device__ __forceinline__ int rl(int v, int j) {
    return __builtin_amdgcn_readlane(v, j);
}
__device__ __forceinline__ float rlf(int v, int j) {
    return __uint_as_float((unsigned)__builtin_amdgcn_readlane(v, j));
}
__device__ __forceinline__ unsigned f2bf(float f) {  // f32 -> bf16 bits, RNE
    unsigned u = __float_as_uint(f);
    return (u + 0x7fffu + ((u >> 16) & 1u)) >> 16;
}
__device__ __forceinline__ f32x2 bf2f(unsigned u) {
    f32x2 r = {__uint_as_float(u << 16), __uint_as_float(u & 0xffff0000u)};
    return r;
}

// meta.x layout: bits[31:26] = local row (0..63), bits[25:8] = col*256 (byte
// offset of the xb row), bits[7:0] = 0.
#define META_OFF_MASK 0x03FFFF00

// ---------------------------------------------------------------------------
// prep (0 LDS, full occupancy): three block-ranges.
//  [0, PB)       : per-row L1 norm of x; pack xb = bf16x2(x*rnorm); xnorm
//  [PB, PB+32)   : Wb bf16 pack, B-fragment layout, XOR-swizzled
//  [PB+32, +1)   : zero the NB relative bucket cursors
// ---------------------------------------------------------------------------
__global__ void prep_kernel(const float* __restrict__ x,
                            unsigned* __restrict__ xb,
                            float* __restrict__ xnorm,
                            const float* __restrict__ W,
                            unsigned* __restrict__ Wb,
                            int* __restrict__ cursor,
                            int N, int PB, int NB) {
    int bid = blockIdx.x;
    int tid = threadIdx.x;
    if (bid < PB) {
        int row = bid * 4 + (tid >> 6);
        int lane = tid & 63;
        if (row >= N) return;
        float2 v = *((const float2*)(x + (size_t)row * HD) + lane);
        float s = fabsf(v.x) + fabsf(v.y);
#pragma unroll
        for (int m = 1; m < 64; m <<= 1) s += __shfl_xor(s, m, 64);
        float nm = fmaxf(s, 1e-12f);
        float rn = 1.0f / nm;
        if (lane == 0) xnorm[row] = nm;
        unsigned lo = f2bf(v.x * rn), hi = f2bf(v.y * rn);
        xb[(size_t)row * 64 + lane] = lo | (hi << 16);
    } else if (bid < PB + 32) {
        int t = (bid - PB) * 256 + tid;  // 0..8191 => (col, k2)
        int col = t >> 6, k2 = t & 63;
        float w0 = W[col * HD + 2 * k2];
        float w1 = W[col * HD + 2 * k2 + 1];
        unsigned pk = f2bf(w0) | (f2bf(w1) << 16);
        int byte = (col * 256 + k2 * 4) ^ ((col & 7) << 4);
        *(unsigned*)((char*)Wb + byte) = pk;
    } else {
        for (int i = tid; i < NB; i += 256) cursor[i] = 0;
    }
}

// ---------------------------------------------------------------------------
// scatter (48KB LDS, own kernel): two-pass ranked scatter into per-bucket
// fixed-capacity slots (bucket b's slot = d_out window b; last bucket -> ws).
// Relative cursors; final cursor value IS the bucket count (no hist/scan).
// ---------------------------------------------------------------------------
__global__ void __launch_bounds__(512) scatter_kernel(
    const int* __restrict__ rows, const int* __restrict__ cols,
    const float* __restrict__ vals, int* __restrict__ cursor,
    int2* __restrict__ outslots, int2* __restrict__ lastslot, int E, int NB) {
    int tid = threadIdx.x;
    if (NB <= NBMAX) {
        __shared__ int lbin[NBMAX];
        __shared__ int lbase[NBMAX];
        __shared__ unsigned short rk16[EPB];
        for (int i = tid; i < NBMAX; i += 512) lbin[i] = 0;
        __syncthreads();
        const int4* rows4 = (const int4*)rows;
        int E4 = E >> 2;
        int base4 = blockIdx.x * (EPB / 4);
        // pass A: local ranks
#pragma unroll
        for (int i = 0; i < 8; ++i) {
            int e4 = base4 + i * 512 + tid;
            if (e4 < E4) {
                int4 r = rows4[e4];
                int li = (i * 512 + tid) * 4;
                rk16[li + 0] = (unsigned short)atomicAdd(&lbin[r.x >> 6], 1);
                rk16[li + 1] = (unsigned short)atomicAdd(&lbin[r.y >> 6], 1);
                rk16[li + 2] = (unsigned short)atomicAdd(&lbin[r.z >> 6], 1);
                rk16[li + 3] = (unsigned short)atomicAdd(&lbin[r.w >> 6], 1);
            }
        }
        __syncthreads();
        // reserve contiguous ranges (relative cursors)
        for (int i = tid; i < NB; i += 512) {
            int c = lbin[i];
            if (c) lbase[i] = atomicAdd(&cursor[i], c);
        }
        __syncthreads();
        // pass B: write edges to reserved slots
        const int4* cols4 = (const int4*)cols;
        const float4* vals4 = (const float4*)vals;
#pragma unroll
        for (int i = 0; i < 8; ++i) {
            int e4 = base4 + i * 512 + tid;
            if (e4 < E4) {
                int4 r4 = rows4[e4];
                int4 c4 = cols4[e4];
                float4 v4 = vals4[e4];
                int li = (i * 512 + tid) * 4;
                int ra[4] = {r4.x, r4.y, r4.z, r4.w};
                int ca[4] = {c4.x, c4.y, c4.z, c4.w};
                float va[4] = {v4.x, v4.y, v4.z, v4.w};
#pragma unroll
                for (int k = 0; k < 4; ++k) {
                    int r = ra[k];
                    int bkt = r >> 6;
                    int idx = lbase[bkt] + rk16[li + k];
                    if (idx < CAP) {
                        int2* sp = (bkt == NB - 1)
                                       ? lastslot
                                       : outslots + (size_t)bkt * SLOT_STRIDE;
                        sp[idx] = make_int2((ca[k] << 8) | ((r & 63) << 26),
                                            __float_as_int(va[k]));
                    }
                }
            }
        }
        if (blockIdx.x == 0) {  // scalar tail (E % 4): direct cursor append
            for (int e = (E & ~3) + tid; e < E; e += 512) {
                int r = rows[e];
                int bkt = r >> 6;
                int rel = atomicAdd(&cursor[bkt], 1);
                if (rel < CAP) {
                    int2* sp = (bkt == NB - 1)
                                   ? lastslot
                                   : outslots + (size_t)bkt * SLOT_STRIDE;
                    sp[rel] = make_int2((cols[e] << 8) | ((r & 63) << 26),
                                        __float_as_int(vals[e]));
                }
            }
        }
    } else {  // fallback: per-edge cursor atomics
        int base = blockIdx.x * EPB;
        for (int i = 0; i < 32; ++i) {
            int e = base + i * 512 + tid;
            if (e >= E) break;
            int r = rows[e];
            int bkt = r >> 6;
            int rel = atomicAdd(&cursor[bkt], 1);
            if (rel < CAP) {
                int2* sp = (bkt == NB - 1)
                               ? lastslot
                               : outslots + (size_t)bkt * SLOT_STRIDE;
                sp[rel] = make_int2((cols[e] << 8) | ((r & 63) << 26),
                                    __float_as_int(vals[e]));
            }
        }
    }
}

// ---------------------------------------------------------------------------
// mega: per 64-row bucket (1024 threads = 16 waves):
//  1. slot edges (in d_out window) -> regs; in-LDS 64-bin counting sort
//  2. gather: each wave accumulates 4 f-rows (f32x2 FMA, 4-wide unroll)
//  3. f -> bf16 -> swizzled LDS A-tile
//  4. GEMM via mfma_f32_16x16x32_bf16 (wave = 16x32 output tile)
//  5. bias, row-L1 reduce, relu, residual (reconstructed from xb*xnorm), store
// Safe d_out reuse: the block fully consumes its slot (phase 1) before any
// out-write, and only ever writes its own 32KB window.
// ---------------------------------------------------------------------------
__global__ void __launch_bounds__(1024) mega_kernel(
    const unsigned* __restrict__ xb, const float* __restrict__ xnorm,
    const int* __restrict__ cursor, const int2* __restrict__ lastslot,
    const unsigned* __restrict__ Wb, const float* __restrict__ bias,
    const float* __restrict__ tsp, float* out, int N, int NB) {
    __shared__ char wb_raw[HD * HD * 2];     // 32 KiB bf16 W, B-layout, swz
    __shared__ char fb_raw[BROWS * HD * 2];  // 16 KiB bf16 F, A-layout, swz
    __shared__ int2 sorted[CAP];             // 16 KiB
    __shared__ int lcnt[BROWS], lbeg[BROWS], lcur[BROWS];
    __shared__ float rowsum[BROWS];

    int tid = threadIdx.x;
    int bid = blockIdx.x;
    const int2* slot = (bid == NB - 1)
                           ? lastslot
                           : (const int2*)((const char*)out +
                                           (size_t)bid * SLOT_BYTES);
    int ct = cursor[bid];
    if (ct > CAP) ct = CAP;

    if (tid < BROWS) lcnt[tid] = 0;

    // phase 1: slot edges -> registers (slot fully consumed here)
    int2 m0 = make_int2(0, 0), m1 = make_int2(0, 0);
    bool e0 = tid < ct, e1 = tid + 1024 < ct;
    if (e0) m0 = slot[tid];
    if (e1) m1 = slot[tid + 1024];
    __syncthreads();

    // phase 2: LDS histogram of local rows
    if (e0) atomicAdd(&lcnt[(unsigned)m0.x >> 26], 1);
    if (e1) atomicAdd(&lcnt[(unsigned)m1.x >> 26], 1);
    __syncthreads();

    // phase 3: wave 0 exclusive-scans the 64 counts
    if (tid < 64) {
        int c = lcnt[tid];
        int s = c;
#pragma unroll
        for (int m = 1; m < 64; m <<= 1) {
            int t2 = __shfl_up(s, m, 64);
            if (tid >= m) s += t2;
        }
        lbeg[tid] = s - c;
        lcur[tid] = s - c;
    }
    __syncthreads();

    // phase 4: scatter edges into LDS-sorted local CSR (+ stage Wb)
    if (e0) {
        int p = atomicAdd(&lcur[(unsigned)m0.x >> 26], 1);
        if (p < CAP) sorted[p] = m0;
    }
    if (e1) {
        int p = atomicAdd(&lcur[(unsigned)m1.x >> 26], 1);
        if (p < CAP) sorted[p] = m1;
    }
    {
        const float4* s4 = (const float4*)Wb;
        float4* d4 = (float4*)wb_raw;
        for (int i = tid; i < HD * HD * 2 / 16; i += 1024) d4[i] = s4[i];
    }
    __syncthreads();

    int lane = tid & 63;
    int wid = tid >> 6;
    float ts = tsp[0];
    const char* xbl = (const char*)xb + (lane << 2);

    // ---- gather: accumulate 4 f-rows (f32x2) per wave ----
    float a0[4], a1[4];
#pragma unroll
    for (int rr = 0; rr < 4; ++rr) {
        int lr = wid * 4 + rr;
        int beg = lbeg[lr], cnt = lcnt[lr];
        f32x2 pq0 = {0.f, 0.f}, pq1 = {0.f, 0.f};
        for (int jb = 0; jb < cnt; jb += 64) {
            int rem = cnt - jb;
            if (rem > 64) rem = 64;
            int2 meta = make_int2(0, 0);
            if (lane < rem) meta = sorted[beg + jb + lane];
            int j = 0;
            for (; j + 4 <= rem; j += 4) {
                int o0 = rl(meta.x, j) & META_OFF_MASK;
                int o1 = rl(meta.x, j + 1) & META_OFF_MASK;
                int o2 = rl(meta.x, j + 2) & META_OFF_MASK;
                int o3 = rl(meta.x, j + 3) & META_OFF_MASK;
                float s0 = rlf(meta.y, j), s1 = rlf(meta.y, j + 1);
                float s2 = rlf(meta.y, j + 2), s3 = rlf(meta.y, j + 3);
                unsigned u0 = *(const unsigned*)(xbl + o0);
                unsigned u1 = *(const unsigned*)(xbl + o1);
                unsigned u2 = *(const unsigned*)(xbl + o2);
                unsigned u3 = *(const unsigned*)(xbl + o3);
                pq0 += bf2f(u0) * s0;
                pq1 += bf2f(u1) * s1;
                pq0 += bf2f(u2) * s2;
                pq1 += bf2f(u3) * s3;
            }
            for (; j < rem; ++j) {
                int o0 = rl(meta.x, j) & META_OFF_MASK;
                float s0 = rlf(meta.y, j);
                unsigned u0 = *(const unsigned*)(xbl + o0);
                pq0 += bf2f(u0) * s0;
            }
        }
        a0[rr] = pq0.x + pq1.x;
        a1[rr] = pq0.y + pq1.y;
    }

    // ---- phase C: f -> bf16 swizzled LDS A-tile; init rowsum ----
#pragma unroll
    for (int rr = 0; rr < 4; ++rr) {
        int row = wid * 4 + rr;  // local row
        unsigned pk = f2bf(a0[rr]) | (f2bf(a1[rr]) << 16);
        int byte = (row * 256 + lane * 4) ^ ((row & 7) << 4);
        *(unsigned*)(fb_raw + byte) = pk;
    }
    if (tid < BROWS) rowsum[tid] = 0.f;
    __syncthreads();

    // ---- MFMA GEMM: wave -> 16-row x 32-col output tile ----
    int rt = wid >> 2;        // row-tile 0..3
    int ct0 = (wid & 3) * 2;  // first col-tile (of 8)
    int c = lane & 15;
    int kg = lane >> 4;
    int arow = rt * 16 + c;
    int bcol0 = ct0 * 16 + c;
    int bcol1 = bcol0 + 16;
    f32x4 acc0 = {0.f, 0.f, 0.f, 0.f}, acc1 = {0.f, 0.f, 0.f, 0.f};
#pragma unroll
    for (int kk = 0; kk < 4; ++kk) {
        int ka = kg * 16 + kk * 64;  // byte offset of this lane's k-chunk
        short8v af = *(const short8v*)(fb_raw +
                                       ((arow * 256 + ka) ^ ((arow & 7) << 4)));
        short8v bf0 = *(const short8v*)(wb_raw +
                                        ((bcol0 * 256 + ka) ^ ((bcol0 & 7) << 4)));
        short8v bf1 = *(const short8v*)(wb_raw +
                                        ((bcol1 * 256 + ka) ^ ((bcol1 & 7) << 4)));
        acc0 = __builtin_amdgcn_mfma_f32_16x16x32_bf16(af, bf0, acc0, 0, 0, 0);
        acc1 = __builtin_amdgcn_mfma_f32_16x16x32_bf16(af, bf1, acc1, 0, 0, 0);
    }

    // ---- epilogue: bias, row-L1 reduce, normalize, relu, residual ----
    float bias0 = bias[bcol0];
    float bias1 = bias[bcol1];
    float g0r[4], g1r[4];
#pragma unroll
    for (int r = 0; r < 4; ++r) {
        float v0 = acc0[r] + bias0;
        float v1 = acc1[r] + bias1;
        g0r[r] = v0;
        g1r[r] = v1;
        float s = fabsf(v0) + fabsf(v1);
        s += __shfl_xor(s, 1, 64);
        s += __shfl_xor(s, 2, 64);
        s += __shfl_xor(s, 4, 64);
        s += __shfl_xor(s, 8, 64);
        if (c == 0) atomicAdd(&rowsum[rt * 16 + kg * 4 + r], s);
    }
    __syncthreads();
#pragma unroll
    for (int r = 0; r < 4; ++r) {
        int lrow = rt * 16 + kg * 4 + r;
        int row = bid * BROWS + lrow;
        if (row < N) {
            float rn = 1.0f / fmaxf(rowsum[lrow], 1e-12f);
            float G0 = fmaxf(g0r[r] * rn, 0.f);
            float G1 = fmaxf(g1r[r] * rn, 0.f);
            // residual reconstruction: x = bf16(x * (1/norm)) * norm
            float nm = xnorm[row];
            unsigned u0 = xb[(size_t)row * 64 + ct0 * 8 + (c >> 1)];
            unsigned u1 = xb[(size_t)row * 64 + ct0 * 8 + 8 + (c >> 1)];
            unsigned h0 = (c & 1) ? (u0 & 0xffff0000u) : (u0 << 16);
            unsigned h1 = (c & 1) ? (u1 & 0xffff0000u) : (u1 << 16);
            float x0 = __uint_as_float(h0) * nm;
            float x1 = __uint_as_float(h1) * nm;
            out[(size_t)row * HD + bcol0] = fmaf(ts, G0, x0);
            out[(size_t)row * HD + bcol1] = fmaf(ts, G1, x1);
        }
    }
}

extern "C" void kernel_launch(void* const* d_in, const int* in_sizes, int n_in,
                              void* d_out, int out_size, void* d_ws,
                              size_t ws_size, hipStream_t stream) {
    const float* x = (const float*)d_in[0];
    const int* Ar = (const int*)d_in[1];
    const int* Ac = (const int*)d_in[2];
    const float* Av = (const float*)d_in[3];
    const float* W = (const float*)d_in[4];
    const float* b = (const float*)d_in[5];
    const float* ts = (const float*)d_in[6];

    int N = in_sizes[0] / HD;
    int E = in_sizes[1];
    float* out = (float*)d_out;

    int NB = (N + BROWS - 1) / BROWS;

    char* ws = (char*)d_ws;
    size_t o = 0;
    auto take = [&](size_t bytes) {
        void* p = ws + o;
        o += (bytes + 511) & ~(size_t)511;
        return p;
    };
    int* cursor = (int*)take((size_t)NB * 4);
    float* xnorm = (float*)take((size_t)N * 4);
    unsigned* Wb = (unsigned*)take((size_t)HD * HD * 2);
    int2* lastslot = (int2*)take((size_t)CAP * 8);
    unsigned* xb = (unsigned*)take((size_t)N * 64 * 4);
    // total ws use ~26.3 MB

    int PB = (N + 3) / 4;
    int SB = (E + EPB - 1) / EPB;

    prep_kernel<<<PB + 33, 256, 0, stream>>>(x, xb, xnorm, W, Wb, cursor, N, PB,
                                             NB);
    scatter_kernel<<<SB, 512, 0, stream>>>(Ar, Ac, Av, cursor, (int2*)d_out,
                                           lastslot, E, NB);
    mega_kernel<<<NB, 1024, 0, stream>>>(xb, xnorm, cursor, lastslot, Wb, b, ts,
                                         out, N, NB);
}

// Round 13
// 129.255 us; speedup vs baseline: 1.2165x; 1.0289x over previous
//
#include <hip/hip_runtime.h>

constexpr int HD = 128;       // hidden size
constexpr int BROWS = 64;     // rows per bucket == rows per mega-block
constexpr int CAP = 2048;     // entries per bucket slot (= LDS sort capacity)
constexpr int NBMAX = 2048;   // max buckets (N <= 131072)
constexpr int EPB = 16384;    // edges per scatter block
constexpr int SLOT_STRIDE = 4096;   // int2 entries per bucket window in d_out
constexpr int SLOT_BYTES = 32768;   // 64 rows * 128 * 4 B

typedef __attribute__((ext_vector_type(8))) short short8v;  // 8 bf16 (4 VGPR)
typedef __attribute__((ext_vector_type(4))) float f32x4;
typedef __attribute__((ext_vector_type(2))) float f32x2;

__device__ __forceinline__ int rl(int v, int j) {
    return __builtin_amdgcn_readlane(v, j);
}
__device__ __forceinline__ float rlf(int v, int j) {
    return __uint_as_float((unsigned)__builtin_amdgcn_readlane(v, j));
}
__device__ __forceinline__ unsigned f2bf(float f) {  // f32 -> bf16 bits, RNE
    unsigned u = __float_as_uint(f);
    return (u + 0x7fffu + ((u >> 16) & 1u)) >> 16;
}
__device__ __forceinline__ f32x2 bf2f(unsigned u) {
    f32x2 r = {__uint_as_float(u << 16), __uint_as_float(u & 0xffff0000u)};
    return r;
}

// meta.x layout: bits[31:26] = local row (0..63), bits[25:8] = col*256 (byte
// offset of the xb row), bits[7:0] = 0.
#define META_OFF_MASK 0x03FFFF00

// ---------------------------------------------------------------------------
// prep (0 LDS, full occupancy): three block-ranges.
//  [0, PB)       : per-row L1 norm of x (float4/lane, 2 rows per wave);
//                  pack xb = bf16x2(x*rnorm) as uint2/lane; store xnorm
//  [PB, PB+32)   : Wb bf16 pack, B-fragment layout, XOR-swizzled
//  [PB+32, +1)   : zero the NB relative bucket cursors
// ---------------------------------------------------------------------------
__global__ void prep_kernel(const float* __restrict__ x,
                            unsigned* __restrict__ xb,
                            float* __restrict__ xnorm,
                            const float* __restrict__ W,
                            unsigned* __restrict__ Wb,
                            int* __restrict__ cursor,
                            int N, int PB, int NB) {
    int bid = blockIdx.x;
    int tid = threadIdx.x;
    if (bid < PB) {
        int wid = tid >> 6;
        int lane = tid & 63;
        int row = bid * 8 + wid * 2 + (lane >> 5);  // 2 rows per wave
        if (row >= N) return;
        int l32 = lane & 31;
        float4 v = *((const float4*)(x + (size_t)row * HD) + l32);
        float s = fabsf(v.x) + fabsf(v.y) + fabsf(v.z) + fabsf(v.w);
        // reduce within each 32-lane half (masks < 32 stay in-group)
        s += __shfl_xor(s, 1, 64);
        s += __shfl_xor(s, 2, 64);
        s += __shfl_xor(s, 4, 64);
        s += __shfl_xor(s, 8, 64);
        s += __shfl_xor(s, 16, 64);
        float nm = fmaxf(s, 1e-12f);
        float rn = 1.0f / nm;
        if (l32 == 0) xnorm[row] = nm;
        uint2 pk;
        pk.x = f2bf(v.x * rn) | (f2bf(v.y * rn) << 16);
        pk.y = f2bf(v.z * rn) | (f2bf(v.w * rn) << 16);
        *((uint2*)(xb + (size_t)row * 64) + l32) = pk;
    } else if (bid < PB + 32) {
        int t = (bid - PB) * 256 + tid;  // 0..8191 => (col, k2)
        int col = t >> 6, k2 = t & 63;
        float w0 = W[col * HD + 2 * k2];
        float w1 = W[col * HD + 2 * k2 + 1];
        unsigned pk = f2bf(w0) | (f2bf(w1) << 16);
        int byte = (col * 256 + k2 * 4) ^ ((col & 7) << 4);
        *(unsigned*)((char*)Wb + byte) = pk;
    } else {
        for (int i = tid; i < NB; i += 256) cursor[i] = 0;
    }
}

// ---------------------------------------------------------------------------
// scatter (48KB LDS, own kernel): two-pass ranked scatter into per-bucket
// fixed-capacity slots (bucket b's slot = d_out window b; last bucket -> ws).
// Relative cursors; final cursor value IS the bucket count (no hist/scan).
// ---------------------------------------------------------------------------
__global__ void __launch_bounds__(512) scatter_kernel(
    const int* __restrict__ rows, const int* __restrict__ cols,
    const float* __restrict__ vals, int* __restrict__ cursor,
    int2* __restrict__ outslots, int2* __restrict__ lastslot, int E, int NB) {
    int tid = threadIdx.x;
    if (NB <= NBMAX) {
        __shared__ int lbin[NBMAX];
        __shared__ int lbase[NBMAX];
        __shared__ unsigned short rk16[EPB];
        for (int i = tid; i < NBMAX; i += 512) lbin[i] = 0;
        __syncthreads();
        const int4* rows4 = (const int4*)rows;
        int E4 = E >> 2;
        int base4 = blockIdx.x * (EPB / 4);
        // pass A: local ranks
#pragma unroll
        for (int i = 0; i < 8; ++i) {
            int e4 = base4 + i * 512 + tid;
            if (e4 < E4) {
                int4 r = rows4[e4];
                int li = (i * 512 + tid) * 4;
                rk16[li + 0] = (unsigned short)atomicAdd(&lbin[r.x >> 6], 1);
                rk16[li + 1] = (unsigned short)atomicAdd(&lbin[r.y >> 6], 1);
                rk16[li + 2] = (unsigned short)atomicAdd(&lbin[r.z >> 6], 1);
                rk16[li + 3] = (unsigned short)atomicAdd(&lbin[r.w >> 6], 1);
            }
        }
        __syncthreads();
        // reserve contiguous ranges (relative cursors)
        for (int i = tid; i < NB; i += 512) {
            int c = lbin[i];
            if (c) lbase[i] = atomicAdd(&cursor[i], c);
        }
        __syncthreads();
        // pass B: write edges to reserved slots
        const int4* cols4 = (const int4*)cols;
        const float4* vals4 = (const float4*)vals;
#pragma unroll
        for (int i = 0; i < 8; ++i) {
            int e4 = base4 + i * 512 + tid;
            if (e4 < E4) {
                int4 r4 = rows4[e4];
                int4 c4 = cols4[e4];
                float4 v4 = vals4[e4];
                int li = (i * 512 + tid) * 4;
                int ra[4] = {r4.x, r4.y, r4.z, r4.w};
                int ca[4] = {c4.x, c4.y, c4.z, c4.w};
                float va[4] = {v4.x, v4.y, v4.z, v4.w};
#pragma unroll
                for (int k = 0; k < 4; ++k) {
                    int r = ra[k];
                    int bkt = r >> 6;
                    int idx = lbase[bkt] + rk16[li + k];
                    if (idx < CAP) {
                        int2* sp = (bkt == NB - 1)
                                       ? lastslot
                                       : outslots + (size_t)bkt * SLOT_STRIDE;
                        sp[idx] = make_int2((ca[k] << 8) | ((r & 63) << 26),
                                            __float_as_int(va[k]));
                    }
                }
            }
        }
        if (blockIdx.x == 0) {  // scalar tail (E % 4): direct cursor append
            for (int e = (E & ~3) + tid; e < E; e += 512) {
                int r = rows[e];
                int bkt = r >> 6;
                int rel = atomicAdd(&cursor[bkt], 1);
                if (rel < CAP) {
                    int2* sp = (bkt == NB - 1)
                                   ? lastslot
                                   : outslots + (size_t)bkt * SLOT_STRIDE;
                    sp[rel] = make_int2((cols[e] << 8) | ((r & 63) << 26),
                                        __float_as_int(vals[e]));
                }
            }
        }
    } else {  // fallback: per-edge cursor atomics
        int base = blockIdx.x * EPB;
        for (int i = 0; i < 32; ++i) {
            int e = base + i * 512 + tid;
            if (e >= E) break;
            int r = rows[e];
            int bkt = r >> 6;
            int rel = atomicAdd(&cursor[bkt], 1);
            if (rel < CAP) {
                int2* sp = (bkt == NB - 1)
                               ? lastslot
                               : outslots + (size_t)bkt * SLOT_STRIDE;
                sp[rel] = make_int2((cols[e] << 8) | ((r & 63) << 26),
                                    __float_as_int(vals[e]));
            }
        }
    }
}

// ---------------------------------------------------------------------------
// mega: per 64-row bucket (1024 threads = 16 waves):
//  1. slot edges (in d_out window) -> regs; in-LDS 64-bin counting sort
//  2. gather: each wave accumulates 4 f-rows (f32x2 FMA, 4-wide unroll)
//  3. f -> bf16 -> swizzled LDS A-tile
//  4. GEMM via mfma_f32_16x16x32_bf16 (wave = 16x32 output tile)
//  5. bias, row-L1 reduce, relu, residual (reconstructed from xb*xnorm), store
// Safe d_out reuse: the block fully consumes its slot (phase 1) before any
// out-write, and only ever writes its own 32KB window.
// ---------------------------------------------------------------------------
__global__ void __launch_bounds__(1024) mega_kernel(
    const unsigned* __restrict__ xb, const float* __restrict__ xnorm,
    const int* __restrict__ cursor, const int2* __restrict__ lastslot,
    const unsigned* __restrict__ Wb, const float* __restrict__ bias,
    const float* __restrict__ tsp, float* out, int N, int NB) {
    __shared__ char wb_raw[HD * HD * 2];     // 32 KiB bf16 W, B-layout, swz
    __shared__ char fb_raw[BROWS * HD * 2];  // 16 KiB bf16 F, A-layout, swz
    __shared__ int2 sorted[CAP];             // 16 KiB
    __shared__ int lcnt[BROWS], lbeg[BROWS], lcur[BROWS];
    __shared__ float rowsum[BROWS];

    int tid = threadIdx.x;
    int bid = blockIdx.x;
    const int2* slot = (bid == NB - 1)
                           ? lastslot
                           : (const int2*)((const char*)out +
                                           (size_t)bid * SLOT_BYTES);
    int ct = cursor[bid];
    if (ct > CAP) ct = CAP;

    if (tid < BROWS) lcnt[tid] = 0;

    // phase 1: slot edges -> registers (slot fully consumed here)
    int2 m0 = make_int2(0, 0), m1 = make_int2(0, 0);
    bool e0 = tid < ct, e1 = tid + 1024 < ct;
    if (e0) m0 = slot[tid];
    if (e1) m1 = slot[tid + 1024];
    __syncthreads();

    // phase 2: LDS histogram of local rows
    if (e0) atomicAdd(&lcnt[(unsigned)m0.x >> 26], 1);
    if (e1) atomicAdd(&lcnt[(unsigned)m1.x >> 26], 1);
    __syncthreads();

    // phase 3: wave 0 exclusive-scans the 64 counts
    if (tid < 64) {
        int c = lcnt[tid];
        int s = c;
#pragma unroll
        for (int m = 1; m < 64; m <<= 1) {
            int t2 = __shfl_up(s, m, 64);
            if (tid >= m) s += t2;
        }
        lbeg[tid] = s - c;
        lcur[tid] = s - c;
    }
    __syncthreads();

    // phase 4: scatter edges into LDS-sorted local CSR (+ stage Wb)
    if (e0) {
        int p = atomicAdd(&lcur[(unsigned)m0.x >> 26], 1);
        if (p < CAP) sorted[p] = m0;
    }
    if (e1) {
        int p = atomicAdd(&lcur[(unsigned)m1.x >> 26], 1);
        if (p < CAP) sorted[p] = m1;
    }
    {
        const float4* s4 = (const float4*)Wb;
        float4* d4 = (float4*)wb_raw;
        for (int i = tid; i < HD * HD * 2 / 16; i += 1024) d4[i] = s4[i];
    }
    __syncthreads();

    int lane = tid & 63;
    int wid = tid >> 6;
    float ts = tsp[0];
    const char* xbl = (const char*)xb + (lane << 2);

    // ---- gather: accumulate 4 f-rows (f32x2) per wave ----
    float a0[4], a1[4];
#pragma unroll
    for (int rr = 0; rr < 4; ++rr) {
        int lr = wid * 4 + rr;
        int beg = lbeg[lr], cnt = lcnt[lr];
        f32x2 pq0 = {0.f, 0.f}, pq1 = {0.f, 0.f};
        for (int jb = 0; jb < cnt; jb += 64) {
            int rem = cnt - jb;
            if (rem > 64) rem = 64;
            int2 meta = make_int2(0, 0);
            if (lane < rem) meta = sorted[beg + jb + lane];
            int j = 0;
            for (; j + 4 <= rem; j += 4) {
                int o0 = rl(meta.x, j) & META_OFF_MASK;
                int o1 = rl(meta.x, j + 1) & META_OFF_MASK;
                int o2 = rl(meta.x, j + 2) & META_OFF_MASK;
                int o3 = rl(meta.x, j + 3) & META_OFF_MASK;
                float s0 = rlf(meta.y, j), s1 = rlf(meta.y, j + 1);
                float s2 = rlf(meta.y, j + 2), s3 = rlf(meta.y, j + 3);
                unsigned u0 = *(const unsigned*)(xbl + o0);
                unsigned u1 = *(const unsigned*)(xbl + o1);
                unsigned u2 = *(const unsigned*)(xbl + o2);
                unsigned u3 = *(const unsigned*)(xbl + o3);
                pq0 += bf2f(u0) * s0;
                pq1 += bf2f(u1) * s1;
                pq0 += bf2f(u2) * s2;
                pq1 += bf2f(u3) * s3;
            }
            for (; j < rem; ++j) {
                int o0 = rl(meta.x, j) & META_OFF_MASK;
                float s0 = rlf(meta.y, j);
                unsigned u0 = *(const unsigned*)(xbl + o0);
                pq0 += bf2f(u0) * s0;
            }
        }
        a0[rr] = pq0.x + pq1.x;
        a1[rr] = pq0.y + pq1.y;
    }

    // ---- phase C: f -> bf16 swizzled LDS A-tile; init rowsum ----
#pragma unroll
    for (int rr = 0; rr < 4; ++rr) {
        int row = wid * 4 + rr;  // local row
        unsigned pk = f2bf(a0[rr]) | (f2bf(a1[rr]) << 16);
        int byte = (row * 256 + lane * 4) ^ ((row & 7) << 4);
        *(unsigned*)(fb_raw + byte) = pk;
    }
    if (tid < BROWS) rowsum[tid] = 0.f;
    __syncthreads();

    // ---- MFMA GEMM: wave -> 16-row x 32-col output tile ----
    int rt = wid >> 2;        // row-tile 0..3
    int ct0 = (wid & 3) * 2;  // first col-tile (of 8)
    int c = lane & 15;
    int kg = lane >> 4;
    int arow = rt * 16 + c;
    int bcol0 = ct0 * 16 + c;
    int bcol1 = bcol0 + 16;
    f32x4 acc0 = {0.f, 0.f, 0.f, 0.f}, acc1 = {0.f, 0.f, 0.f, 0.f};
#pragma unroll
    for (int kk = 0; kk < 4; ++kk) {
        int ka = kg * 16 + kk * 64;  // byte offset of this lane's k-chunk
        short8v af = *(const short8v*)(fb_raw +
                                       ((arow * 256 + ka) ^ ((arow & 7) << 4)));
        short8v bf0 = *(const short8v*)(wb_raw +
                                        ((bcol0 * 256 + ka) ^ ((bcol0 & 7) << 4)));
        short8v bf1 = *(const short8v*)(wb_raw +
                                        ((bcol1 * 256 + ka) ^ ((bcol1 & 7) << 4)));
        acc0 = __builtin_amdgcn_mfma_f32_16x16x32_bf16(af, bf0, acc0, 0, 0, 0);
        acc1 = __builtin_amdgcn_mfma_f32_16x16x32_bf16(af, bf1, acc1, 0, 0, 0);
    }

    // ---- epilogue: bias, row-L1 reduce, normalize, relu, residual ----
    float bias0 = bias[bcol0];
    float bias1 = bias[bcol1];
    float g0r[4], g1r[4];
#pragma unroll
    for (int r = 0; r < 4; ++r) {
        float v0 = acc0[r] + bias0;
        float v1 = acc1[r] + bias1;
        g0r[r] = v0;
        g1r[r] = v1;
        float s = fabsf(v0) + fabsf(v1);
        s += __shfl_xor(s, 1, 64);
        s += __shfl_xor(s, 2, 64);
        s += __shfl_xor(s, 4, 64);
        s += __shfl_xor(s, 8, 64);
        if (c == 0) atomicAdd(&rowsum[rt * 16 + kg * 4 + r], s);
    }
    __syncthreads();
#pragma unroll
    for (int r = 0; r < 4; ++r) {
        int lrow = rt * 16 + kg * 4 + r;
        int row = bid * BROWS + lrow;
        if (row < N) {
            float rn = 1.0f / fmaxf(rowsum[lrow], 1e-12f);
            float G0 = fmaxf(g0r[r] * rn, 0.f);
            float G1 = fmaxf(g1r[r] * rn, 0.f);
            // residual reconstruction: x = bf16(x * (1/norm)) * norm
            float nm = xnorm[row];
            unsigned u0 = xb[(size_t)row * 64 + ct0 * 8 + (c >> 1)];
            unsigned u1 = xb[(size_t)row * 64 + ct0 * 8 + 8 + (c >> 1)];
            unsigned h0 = (c & 1) ? (u0 & 0xffff0000u) : (u0 << 16);
            unsigned h1 = (c & 1) ? (u1 & 0xffff0000u) : (u1 << 16);
            float x0 = __uint_as_float(h0) * nm;
            float x1 = __uint_as_float(h1) * nm;
            out[(size_t)row * HD + bcol0] = fmaf(ts, G0, x0);
            out[(size_t)row * HD + bcol1] = fmaf(ts, G1, x1);
        }
    }
}

extern "C" void kernel_launch(void* const* d_in, const int* in_sizes, int n_in,
                              void* d_out, int out_size, void* d_ws,
                              size_t ws_size, hipStream_t stream) {
    const float* x = (const float*)d_in[0];
    const int* Ar = (const int*)d_in[1];
    const int* Ac = (const int*)d_in[2];
    const float* Av = (const float*)d_in[3];
    const float* W = (const float*)d_in[4];
    const float* b = (const float*)d_in[5];
    const float* ts = (const float*)d_in[6];

    int N = in_sizes[0] / HD;
    int E = in_sizes[1];
    float* out = (float*)d_out;

    int NB = (N + BROWS - 1) / BROWS;

    char* ws = (char*)d_ws;
    size_t o = 0;
    auto take = [&](size_t bytes) {
        void* p = ws + o;
        o += (bytes + 511) & ~(size_t)511;
        return p;
    };
    int* cursor = (int*)take((size_t)NB * 4);
    float* xnorm = (float*)take((size_t)N * 4);
    unsigned* Wb = (unsigned*)take((size_t)HD * HD * 2);
    int2* lastslot = (int2*)take((size_t)CAP * 8);
    unsigned* xb = (unsigned*)take((size_t)N * 64 * 4);
    // total ws use ~26.3 MB

    int PB = (N + 7) / 8;  // 8 rows per 256-thread prep block (2 per wave)
    int SB = (E + EPB - 1) / EPB;

    prep_kernel<<<PB + 33, 256, 0, stream>>>(x, xb, xnorm, W, Wb, cursor, N, PB,
                                             NB);
    scatter_kernel<<<SB, 512, 0, stream>>>(Ar, Ac, Av, cursor, (int2*)d_out,
                                           lastslot, E, NB);
    mega_kernel<<<NB, 1024, 0, stream>>>(xb, xnorm, cursor, lastslot, Wb, b, ts,
                                         out, N, NB);
}

// Round 14
// 127.388 us; speedup vs baseline: 1.2344x; 1.0147x over previous
//
#include <hip/hip_runtime.h>

constexpr int HD = 128;       // hidden size
constexpr int BROWS = 64;     // rows per bucket == rows per mega-block
constexpr int CAP = 2048;     // entries per bucket slot (= LDS sort capacity)
constexpr int NBMAX = 2048;   // max buckets (N <= 131072)
constexpr int EPB = 16384;    // edges per scatter block
constexpr int SLOT_STRIDE = 4096;   // int2 entries per bucket window in d_out
constexpr int SLOT_BYTES = 32768;   // 64 rows * 128 * 4 B

typedef __attribute__((ext_vector_type(8))) short short8v;  // 8 bf16 (4 VGPR)
typedef __attribute__((ext_vector_type(4))) float f32x4;
typedef __attribute__((ext_vector_type(2))) float f32x2;

__device__ __forceinline__ int rl(int v, int j) {
    return __builtin_amdgcn_readlane(v, j);
}
__device__ __forceinline__ float rlf(int v, int j) {
    return __uint_as_float((unsigned)__builtin_amdgcn_readlane(v, j));
}
__device__ __forceinline__ unsigned f2bf(float f) {  // f32 -> bf16 bits, RNE
    unsigned u = __float_as_uint(f);
    return (u + 0x7fffu + ((u >> 16) & 1u)) >> 16;
}
__device__ __forceinline__ f32x2 bf2f(unsigned u) {
    f32x2 r = {__uint_as_float(u << 16), __uint_as_float(u & 0xffff0000u)};
    return r;
}

// meta.x layout: bits[31:26] = local row (0..63), bits[25:8] = col*256 (byte
// offset of the xb row), bits[7:0] = 0.
#define META_OFF_MASK 0x03FFFF00

// ---------------------------------------------------------------------------
// prep (0 LDS, full occupancy): three block-ranges.
//  [0, PB)       : per-row L1 norm of x (float4/lane, 2 rows per wave);
//                  pack xb = bf16x2(x*rnorm) as uint2/lane; store xnorm
//  [PB, PB+32)   : Wb bf16 pack, B-fragment layout, XOR-swizzled
//  [PB+32, +1)   : zero the NB relative bucket cursors
// ---------------------------------------------------------------------------
__global__ void prep_kernel(const float* __restrict__ x,
                            unsigned* __restrict__ xb,
                            float* __restrict__ xnorm,
                            const float* __restrict__ W,
                            unsigned* __restrict__ Wb,
                            int* __restrict__ cursor,
                            int N, int PB, int NB) {
    int bid = blockIdx.x;
    int tid = threadIdx.x;
    if (bid < PB) {
        int wid = tid >> 6;
        int lane = tid & 63;
        int row = bid * 8 + wid * 2 + (lane >> 5);  // 2 rows per wave
        if (row >= N) return;
        int l32 = lane & 31;
        float4 v = *((const float4*)(x + (size_t)row * HD) + l32);
        float s = fabsf(v.x) + fabsf(v.y) + fabsf(v.z) + fabsf(v.w);
        // reduce within each 32-lane half (masks < 32 stay in-group)
        s += __shfl_xor(s, 1, 64);
        s += __shfl_xor(s, 2, 64);
        s += __shfl_xor(s, 4, 64);
        s += __shfl_xor(s, 8, 64);
        s += __shfl_xor(s, 16, 64);
        float nm = fmaxf(s, 1e-12f);
        float rn = 1.0f / nm;
        if (l32 == 0) xnorm[row] = nm;
        uint2 pk;
        pk.x = f2bf(v.x * rn) | (f2bf(v.y * rn) << 16);
        pk.y = f2bf(v.z * rn) | (f2bf(v.w * rn) << 16);
        *((uint2*)(xb + (size_t)row * 64) + l32) = pk;
    } else if (bid < PB + 32) {
        int t = (bid - PB) * 256 + tid;  // 0..8191 => (col, k2)
        int col = t >> 6, k2 = t & 63;
        float w0 = W[col * HD + 2 * k2];
        float w1 = W[col * HD + 2 * k2 + 1];
        unsigned pk = f2bf(w0) | (f2bf(w1) << 16);
        int byte = (col * 256 + k2 * 4) ^ ((col & 7) << 4);
        *(unsigned*)((char*)Wb + byte) = pk;
    } else {
        for (int i = tid; i < NB; i += 256) cursor[i] = 0;
    }
}

// ---------------------------------------------------------------------------
// scatter (48KB LDS, own kernel): two-pass ranked scatter into per-bucket
// fixed-capacity slots (bucket b's slot = d_out window b; last bucket -> ws).
// Relative cursors; final cursor value IS the bucket count (no hist/scan).
// ---------------------------------------------------------------------------
__global__ void __launch_bounds__(512) scatter_kernel(
    const int* __restrict__ rows, const int* __restrict__ cols,
    const float* __restrict__ vals, int* __restrict__ cursor,
    int2* __restrict__ outslots, int2* __restrict__ lastslot, int E, int NB) {
    int tid = threadIdx.x;
    if (NB <= NBMAX) {
        __shared__ int lbin[NBMAX];
        __shared__ int lbase[NBMAX];
        __shared__ unsigned short rk16[EPB];
        for (int i = tid; i < NBMAX; i += 512) lbin[i] = 0;
        __syncthreads();
        const int4* rows4 = (const int4*)rows;
        int E4 = E >> 2;
        int base4 = blockIdx.x * (EPB / 4);
        // pass A: local ranks
#pragma unroll
        for (int i = 0; i < 8; ++i) {
            int e4 = base4 + i * 512 + tid;
            if (e4 < E4) {
                int4 r = rows4[e4];
                int li = (i * 512 + tid) * 4;
                rk16[li + 0] = (unsigned short)atomicAdd(&lbin[r.x >> 6], 1);
                rk16[li + 1] = (unsigned short)atomicAdd(&lbin[r.y >> 6], 1);
                rk16[li + 2] = (unsigned short)atomicAdd(&lbin[r.z >> 6], 1);
                rk16[li + 3] = (unsigned short)atomicAdd(&lbin[r.w >> 6], 1);
            }
        }
        __syncthreads();
        // reserve contiguous ranges (relative cursors)
        for (int i = tid; i < NB; i += 512) {
            int c = lbin[i];
            if (c) lbase[i] = atomicAdd(&cursor[i], c);
        }
        __syncthreads();
        // pass B: write edges to reserved slots
        const int4* cols4 = (const int4*)cols;
        const float4* vals4 = (const float4*)vals;
#pragma unroll
        for (int i = 0; i < 8; ++i) {
            int e4 = base4 + i * 512 + tid;
            if (e4 < E4) {
                int4 r4 = rows4[e4];
                int4 c4 = cols4[e4];
                float4 v4 = vals4[e4];
                int li = (i * 512 + tid) * 4;
                int ra[4] = {r4.x, r4.y, r4.z, r4.w};
                int ca[4] = {c4.x, c4.y, c4.z, c4.w};
                float va[4] = {v4.x, v4.y, v4.z, v4.w};
#pragma unroll
                for (int k = 0; k < 4; ++k) {
                    int r = ra[k];
                    int bkt = r >> 6;
                    int idx = lbase[bkt] + rk16[li + k];
                    if (idx < CAP) {
                        int2* sp = (bkt == NB - 1)
                                       ? lastslot
                                       : outslots + (size_t)bkt * SLOT_STRIDE;
                        sp[idx] = make_int2((ca[k] << 8) | ((r & 63) << 26),
                                            __float_as_int(va[k]));
                    }
                }
            }
        }
        if (blockIdx.x == 0) {  // scalar tail (E % 4): direct cursor append
            for (int e = (E & ~3) + tid; e < E; e += 512) {
                int r = rows[e];
                int bkt = r >> 6;
                int rel = atomicAdd(&cursor[bkt], 1);
                if (rel < CAP) {
                    int2* sp = (bkt == NB - 1)
                                   ? lastslot
                                   : outslots + (size_t)bkt * SLOT_STRIDE;
                    sp[rel] = make_int2((cols[e] << 8) | ((r & 63) << 26),
                                        __float_as_int(vals[e]));
                }
            }
        }
    } else {  // fallback: per-edge cursor atomics
        int base = blockIdx.x * EPB;
        for (int i = 0; i < 32; ++i) {
            int e = base + i * 512 + tid;
            if (e >= E) break;
            int r = rows[e];
            int bkt = r >> 6;
            int rel = atomicAdd(&cursor[bkt], 1);
            if (rel < CAP) {
                int2* sp = (bkt == NB - 1)
                               ? lastslot
                               : outslots + (size_t)bkt * SLOT_STRIDE;
                sp[rel] = make_int2((cols[e] << 8) | ((r & 63) << 26),
                                    __float_as_int(vals[e]));
            }
        }
    }
}

// ---------------------------------------------------------------------------
// mega: per 64-row bucket (1024 threads = 16 waves):
//  1. slot edges (in d_out window) -> regs; in-LDS 64-bin counting sort
//  2. gather: HALF-WAVE scheme -- lanes 0-31 load edge A's row (8B/lane),
//     lanes 32-63 edge B's; one wave-load covers TWO edges (halves VMEM
//     instruction count vs 4B/lane). Lane accumulates 4 dims in f32x4;
//     one shfl_xor(32) combine per row at the end.
//  3. f -> bf16 -> swizzled LDS A-tile (lower half writes uint2)
//  4. GEMM via mfma_f32_16x16x32_bf16 (wave = 16x32 output tile)
//  5. bias, row-L1 reduce, relu, residual (reconstructed from xb*xnorm), store
// ---------------------------------------------------------------------------
__global__ void __launch_bounds__(1024) mega_kernel(
    const unsigned* __restrict__ xb, const float* __restrict__ xnorm,
    const int* __restrict__ cursor, const int2* __restrict__ lastslot,
    const unsigned* __restrict__ Wb, const float* __restrict__ bias,
    const float* __restrict__ tsp, float* out, int N, int NB) {
    __shared__ char wb_raw[HD * HD * 2];     // 32 KiB bf16 W, B-layout, swz
    __shared__ char fb_raw[BROWS * HD * 2];  // 16 KiB bf16 F, A-layout, swz
    __shared__ int2 sorted[CAP];             // 16 KiB
    __shared__ int lcnt[BROWS], lbeg[BROWS], lcur[BROWS];
    __shared__ float rowsum[BROWS];

    int tid = threadIdx.x;
    int bid = blockIdx.x;
    const int2* slot = (bid == NB - 1)
                           ? lastslot
                           : (const int2*)((const char*)out +
                                           (size_t)bid * SLOT_BYTES);
    int ct = cursor[bid];
    if (ct > CAP) ct = CAP;

    if (tid < BROWS) lcnt[tid] = 0;

    // phase 1: slot edges -> registers (slot fully consumed here)
    int2 m0 = make_int2(0, 0), m1 = make_int2(0, 0);
    bool e0 = tid < ct, e1 = tid + 1024 < ct;
    if (e0) m0 = slot[tid];
    if (e1) m1 = slot[tid + 1024];
    __syncthreads();

    // phase 2: LDS histogram of local rows
    if (e0) atomicAdd(&lcnt[(unsigned)m0.x >> 26], 1);
    if (e1) atomicAdd(&lcnt[(unsigned)m1.x >> 26], 1);
    __syncthreads();

    // phase 3: wave 0 exclusive-scans the 64 counts
    if (tid < 64) {
        int c = lcnt[tid];
        int s = c;
#pragma unroll
        for (int m = 1; m < 64; m <<= 1) {
            int t2 = __shfl_up(s, m, 64);
            if (tid >= m) s += t2;
        }
        lbeg[tid] = s - c;
        lcur[tid] = s - c;
    }
    __syncthreads();

    // phase 4: scatter edges into LDS-sorted local CSR (+ stage Wb)
    if (e0) {
        int p = atomicAdd(&lcur[(unsigned)m0.x >> 26], 1);
        if (p < CAP) sorted[p] = m0;
    }
    if (e1) {
        int p = atomicAdd(&lcur[(unsigned)m1.x >> 26], 1);
        if (p < CAP) sorted[p] = m1;
    }
    {
        const float4* s4 = (const float4*)Wb;
        float4* d4 = (float4*)wb_raw;
        for (int i = tid; i < HD * HD * 2 / 16; i += 1024) d4[i] = s4[i];
    }
    __syncthreads();

    int lane = tid & 63;
    int wid = tid >> 6;
    int half = lane >> 5;   // 0: edges 2j, 1: edges 2j+1
    int l32 = lane & 31;
    float ts = tsp[0];
    const char* xb2 = (const char*)xb + (l32 << 3);  // 8B/lane half-wave base

    // ---- gather: half-wave, 2 edges per wave-load ----
    float a0[4], a1[4], a2[4], a3[4];  // per-row 4-dim accumulators
#pragma unroll
    for (int rr = 0; rr < 4; ++rr) {
        int lr = wid * 4 + rr;
        int beg = lbeg[lr], cnt = lcnt[lr];
        f32x2 p01 = {0.f, 0.f}, p23 = {0.f, 0.f};
        f32x2 q01 = {0.f, 0.f}, q23 = {0.f, 0.f};
        for (int jb = 0; jb < cnt; jb += 64) {
            int rem = cnt - jb;
            if (rem > 64) rem = 64;
            int2 meta = make_int2(0, 0);
            if (lane < rem) meta = sorted[beg + jb + lane];
            int jn = (rem + 1) >> 1;
            int j = 0;
            for (; j + 2 <= jn; j += 2) {  // 2 wave-loads (4 edges) per iter
                int oa0 = rl(meta.x, 2 * j) & META_OFF_MASK;
                int oa1 = rl(meta.x, 2 * j + 1) & META_OFF_MASK;
                int ob0 = rl(meta.x, 2 * j + 2) & META_OFF_MASK;
                int ob1 = rl(meta.x, 2 * j + 3) & META_OFF_MASK;
                float sa0 = rlf(meta.y, 2 * j), sa1 = rlf(meta.y, 2 * j + 1);
                float sb0 = rlf(meta.y, 2 * j + 2), sb1 = rlf(meta.y, 2 * j + 3);
                int oa = half ? oa1 : oa0;
                int ob = half ? ob1 : ob0;
                float sa = half ? sa1 : sa0;
                float sb = half ? sb1 : sb0;
                uint2 ua = *(const uint2*)(xb2 + oa);
                uint2 ub = *(const uint2*)(xb2 + ob);
                p01 += bf2f(ua.x) * sa;
                p23 += bf2f(ua.y) * sa;
                q01 += bf2f(ub.x) * sb;
                q23 += bf2f(ub.y) * sb;
            }
            for (; j < jn; ++j) {
                int o0 = rl(meta.x, 2 * j) & META_OFF_MASK;
                int o1 = rl(meta.x, 2 * j + 1) & META_OFF_MASK;
                float s0 = rlf(meta.y, 2 * j), s1 = rlf(meta.y, 2 * j + 1);
                int o = half ? o1 : o0;
                float s = half ? s1 : s0;
                uint2 u = *(const uint2*)(xb2 + o);
                p01 += bf2f(u.x) * s;
                p23 += bf2f(u.y) * s;
            }
        }
        p01 += q01;
        p23 += q23;
        a0[rr] = p01.x;
        a1[rr] = p01.y;
        a2[rr] = p23.x;
        a3[rr] = p23.y;
    }
    // combine the two half-wave partial sums (per row, 4 dims)
#pragma unroll
    for (int rr = 0; rr < 4; ++rr) {
        a0[rr] += __shfl_xor(a0[rr], 32, 64);
        a1[rr] += __shfl_xor(a1[rr], 32, 64);
        a2[rr] += __shfl_xor(a2[rr], 32, 64);
        a3[rr] += __shfl_xor(a3[rr], 32, 64);
    }

    // ---- phase C: f -> bf16 swizzled LDS A-tile (lower half writes) ----
    if (half == 0) {
#pragma unroll
        for (int rr = 0; rr < 4; ++rr) {
            int row = wid * 4 + rr;  // local row
            uint2 pk;
            pk.x = f2bf(a0[rr]) | (f2bf(a1[rr]) << 16);
            pk.y = f2bf(a2[rr]) | (f2bf(a3[rr]) << 16);
            int byte = (row * 256 + l32 * 8) ^ ((row & 7) << 4);
            *(uint2*)(fb_raw + byte) = pk;
        }
    }
    if (tid < BROWS) rowsum[tid] = 0.f;
    __syncthreads();

    // ---- MFMA GEMM: wave -> 16-row x 32-col output tile ----
    int rt = wid >> 2;        // row-tile 0..3
    int ct0 = (wid & 3) * 2;  // first col-tile (of 8)
    int c = lane & 15;
    int kg = lane >> 4;
    int arow = rt * 16 + c;
    int bcol0 = ct0 * 16 + c;
    int bcol1 = bcol0 + 16;
    f32x4 acc0 = {0.f, 0.f, 0.f, 0.f}, acc1 = {0.f, 0.f, 0.f, 0.f};
#pragma unroll
    for (int kk = 0; kk < 4; ++kk) {
        int ka = kg * 16 + kk * 64;  // byte offset of this lane's k-chunk
        short8v af = *(const short8v*)(fb_raw +
                                       ((arow * 256 + ka) ^ ((arow & 7) << 4)));
        short8v bf0 = *(const short8v*)(wb_raw +
                                        ((bcol0 * 256 + ka) ^ ((bcol0 & 7) << 4)));
        short8v bf1 = *(const short8v*)(wb_raw +
                                        ((bcol1 * 256 + ka) ^ ((bcol1 & 7) << 4)));
        acc0 = __builtin_amdgcn_mfma_f32_16x16x32_bf16(af, bf0, acc0, 0, 0, 0);
        acc1 = __builtin_amdgcn_mfma_f32_16x16x32_bf16(af, bf1, acc1, 0, 0, 0);
    }

    // ---- epilogue: bias, row-L1 reduce, normalize, relu, residual ----
    float bias0 = bias[bcol0];
    float bias1 = bias[bcol1];
    float g0r[4], g1r[4];
#pragma unroll
    for (int r = 0; r < 4; ++r) {
        float v0 = acc0[r] + bias0;
        float v1 = acc1[r] + bias1;
        g0r[r] = v0;
        g1r[r] = v1;
        float s = fabsf(v0) + fabsf(v1);
        s += __shfl_xor(s, 1, 64);
        s += __shfl_xor(s, 2, 64);
        s += __shfl_xor(s, 4, 64);
        s += __shfl_xor(s, 8, 64);
        if (c == 0) atomicAdd(&rowsum[rt * 16 + kg * 4 + r], s);
    }
    __syncthreads();
#pragma unroll
    for (int r = 0; r < 4; ++r) {
        int lrow = rt * 16 + kg * 4 + r;
        int row = bid * BROWS + lrow;
        if (row < N) {
            float rn = 1.0f / fmaxf(rowsum[lrow], 1e-12f);
            float G0 = fmaxf(g0r[r] * rn, 0.f);
            float G1 = fmaxf(g1r[r] * rn, 0.f);
            // residual reconstruction: x = bf16(x * (1/norm)) * norm
            float nm = xnorm[row];
            unsigned u0 = xb[(size_t)row * 64 + ct0 * 8 + (c >> 1)];
            unsigned u1 = xb[(size_t)row * 64 + ct0 * 8 + 8 + (c >> 1)];
            unsigned h0 = (c & 1) ? (u0 & 0xffff0000u) : (u0 << 16);
            unsigned h1 = (c & 1) ? (u1 & 0xffff0000u) : (u1 << 16);
            float x0 = __uint_as_float(h0) * nm;
            float x1 = __uint_as_float(h1) * nm;
            out[(size_t)row * HD + bcol0] = fmaf(ts, G0, x0);
            out[(size_t)row * HD + bcol1] = fmaf(ts, G1, x1);
        }
    }
}

extern "C" void kernel_launch(void* const* d_in, const int* in_sizes, int n_in,
                              void* d_out, int out_size, void* d_ws,
                              size_t ws_size, hipStream_t stream) {
    const float* x = (const float*)d_in[0];
    const int* Ar = (const int*)d_in[1];
    const int* Ac = (const int*)d_in[2];
    const float* Av = (const float*)d_in[3];
    const float* W = (const float*)d_in[4];
    const float* b = (const float*)d_in[5];
    const float* ts = (const float*)d_in[6];

    int N = in_sizes[0] / HD;
    int E = in_sizes[1];
    float* out = (float*)d_out;

    int NB = (N + BROWS - 1) / BROWS;

    char* ws = (char*)d_ws;
    size_t o = 0;
    auto take = [&](size_t bytes) {
        void* p = ws + o;
        o += (bytes + 511) & ~(size_t)511;
        return p;
    };
    int* cursor = (int*)take((size_t)NB * 4);
    float* xnorm = (float*)take((size_t)N * 4);
    unsigned* Wb = (unsigned*)take((size_t)HD * HD * 2);
    int2* lastslot = (int2*)take((size_t)CAP * 8);
    unsigned* xb = (unsigned*)take((size_t)N * 64 * 4);
    // total ws use ~26.3 MB

    int PB = (N + 7) / 8;  // 8 rows per 256-thread prep block (2 per wave)
    int SB = (E + EPB - 1) / EPB;

    prep_kernel<<<PB + 33, 256, 0, stream>>>(x, xb, xnorm, W, Wb, cursor, N, PB,
                                             NB);
    scatter_kernel<<<SB, 512, 0, stream>>>(Ar, Ac, Av, cursor, (int2*)d_out,
                                           lastslot, E, NB);
    mega_kernel<<<NB, 1024, 0, stream>>>(xb, xnorm, cursor, lastslot, Wb, b, ts,
                                         out, N, NB);
}